// Round 1
// baseline (535.409 us; speedup 1.0000x reference)
//
#include <hip/hip_runtime.h>
#include <math.h>

#define NPATCH 2048
#define RES 32
#define NPTS 1024
#define NTOT (NPATCH * NPTS)

__global__ __launch_bounds__(256) void spline_fused(
    const float* __restrict__ cp,       // [P,4,4,3]
    const float* __restrict__ Wt,       // [P,4,4]
    const float* __restrict__ sh_dc,    // [P,4,4,1,3]
    const float* __restrict__ sh_rest,  // [P,4,4,15,3]
    const float* __restrict__ spar,     // [P,2]
    const float* __restrict__ opac,     // [N,1]
    const float* __restrict__ b_u,      // [P,32,4]
    const float* __restrict__ b_v,
    const float* __restrict__ db_u,
    const float* __restrict__ db_v,
    const float* __restrict__ ddb_u,
    const float* __restrict__ ddb_v,
    float* __restrict__ out)
{
    const int a = blockIdx.x;
    const int tid = threadIdx.x;

    __shared__ float s_W[16];
    __shared__ float s_wcp[16][3];
    __shared__ float s_sh[16][48];
    __shared__ float s_bu[32][4];
    __shared__ float s_bv[32][4];
    __shared__ float s_dbu[32][4];
    __shared__ float s_dbv[32][4];
    __shared__ float s_ddbu[32][4];
    __shared__ float s_ddbv[32][4];
    __shared__ float s_red[4];
    __shared__ float s_area;

    if (tid < 16) s_W[tid] = Wt[a * 16 + tid];
    if (tid < 48) {
        const int kl = tid / 3, m = tid - kl * 3;
        s_wcp[kl][m] = cp[a * 48 + tid] * Wt[a * 16 + kl];
    }
    for (int idx = tid; idx < 768; idx += 256) {
        const int kl = idx / 48, c = idx - kl * 48;
        s_sh[kl][c] = (c < 3) ? sh_dc[a * 48 + kl * 3 + c]
                              : sh_rest[a * 720 + kl * 45 + (c - 3)];
    }
    if (tid < 128) {
        s_bu  [tid >> 2][tid & 3] = b_u  [a * 128 + tid];
        s_bv  [tid >> 2][tid & 3] = b_v  [a * 128 + tid];
        s_dbu [tid >> 2][tid & 3] = db_u [a * 128 + tid];
        s_dbv [tid >> 2][tid & 3] = db_v [a * 128 + tid];
        s_ddbu[tid >> 2][tid & 3] = ddb_u[a * 128 + tid];
        s_ddbv[tid >> 2][tid & 3] = ddb_v[a * 128 + tid];
    }
    __syncthreads();

    const long N3 = 3L * NTOT, N4 = 4L * NTOT, N7 = 7L * NTOT, N11 = 11L * NTOT;

    float sxA[4], syA[4], cvxA[4], cvyA[4];
    float buA[4][4], bvA[4][4];
    float area_acc = 0.f;

    #pragma unroll
    for (int s2 = 0; s2 < 4; ++s2) {
        const int pp = tid + s2 * 256;
        const int i = pp >> 5, j = pp & 31;
        float bu[4], bv[4], dbu_[4], dbv_[4], ddbu_[4], ddbv_[4];
        #pragma unroll
        for (int k = 0; k < 4; ++k) {
            bu[k]    = s_bu[i][k];    bv[k]    = s_bv[j][k];
            dbu_[k]  = s_dbu[i][k];   dbv_[k]  = s_dbv[j][k];
            ddbu_[k] = s_ddbu[i][k];  ddbv_[k] = s_ddbv[j][k];
            buA[s2][k] = bu[k];       bvA[s2][k] = bv[k];
        }

        float den = 0.f;
        float x0 = 0, x1 = 0, x2 = 0;
        float du0 = 0, du1 = 0, du2 = 0, dv0 = 0, dv1 = 0, dv2 = 0;
        float eu0 = 0, eu1 = 0, eu2 = 0, ev0 = 0, ev1 = 0, ev2 = 0;
        #pragma unroll
        for (int kl = 0; kl < 16; ++kl) {
            const int k = kl >> 2, l = kl & 3;
            const float bb  = bu[k] * bv[l];
            const float wdu = dbu_[k] * bv[l];
            const float wdv = bu[k] * dbv_[l];
            const float weu = ddbu_[k] * bv[l];
            const float wev = bu[k] * ddbv_[l];
            den += bb * s_W[kl];
            const float c0 = s_wcp[kl][0], c1 = s_wcp[kl][1], c2 = s_wcp[kl][2];
            x0  += bb  * c0; x1  += bb  * c1; x2  += bb  * c2;
            du0 += wdu * c0; du1 += wdu * c1; du2 += wdu * c2;
            dv0 += wdv * c0; dv1 += wdv * c1; dv2 += wdv * c2;
            eu0 += weu * c0; eu1 += weu * c1; eu2 += weu * c2;
            ev0 += wev * c0; ev1 += wev * c1; ev2 += wev * c2;
        }
        if (den == 0.f) den = 1.f;
        const float inv = 1.0f / den;
        x0 *= inv; x1 *= inv; x2 *= inv;
        du0 *= inv; du1 *= inv; du2 *= inv;
        dv0 *= inv; dv1 *= inv; dv2 *= inv;
        eu0 *= inv; eu1 *= inv; eu2 *= inv;
        ev0 *= inv; ev1 *= inv; ev2 *= inv;

        const float cx = du1 * dv2 - du2 * dv1;
        const float cy = du2 * dv0 - du0 * dv2;
        const float cz = du0 * dv1 - du1 * dv0;
        area_acc += sqrtf(cx * cx + cy * cy + cz * cz);

        float l1 = fabsf(cx) + fabsf(cy) + fabsf(cz);
        l1 = fmaxf(l1, 1e-12f);
        float nx = cx / l1, ny = cy / l1, nz = cz / l1;
        float l2 = sqrtf(nx * nx + ny * ny + nz * nz);
        l2 = fmaxf(l2, 1e-12f);
        nx /= l2; ny /= l2; nz /= l2;
        const float qw = 1.f + nz, qx = -ny, qy = nx;
        float qn = sqrtf(qw * qw + qx * qx + qy * qy);
        qn = fmaxf(qn, 1e-12f);

        sxA[s2]  = du0 * du0 + du1 * du1 + du2 * du2 + 10.f;
        syA[s2]  = dv0 * dv0 + dv1 * dv1 + dv2 * dv2 + 10.f;
        cvxA[s2] = eu0 + eu1 + eu2;
        cvyA[s2] = ev0 + ev1 + ev2;

        const long n = (long)a * NPTS + pp;
        out[n * 3 + 0] = x0;
        out[n * 3 + 1] = x1;
        out[n * 3 + 2] = x2;
        out[N3 + n] = opac[n];
        out[N7 + n * 4 + 0] = qw / qn;
        out[N7 + n * 4 + 1] = qx / qn;
        out[N7 + n * 4 + 2] = qy / qn;
        out[N7 + n * 4 + 3] = 0.f;
    }

    // per-patch area mean: wave reduce then cross-wave via LDS
    #pragma unroll
    for (int off = 32; off > 0; off >>= 1)
        area_acc += __shfl_down(area_acc, off, 64);
    if ((tid & 63) == 0) s_red[tid >> 6] = area_acc;
    __syncthreads();
    if (tid == 0) s_area = s_red[0] + s_red[1] + s_red[2] + s_red[3];
    __syncthreads();

    const float factor = s_area * (1.0f / 1024.0f) * (1.0f / 1024.0f); // mean / R^2
    const float sp0 = spar[a * 2 + 0], sp1 = spar[a * 2 + 1];
    const float sf0 = factor * sp0;
    const float sf1 = factor * sp1;
    const float sf2 = factor * 1e-16f;
    const float sc2 = 0.5f * logf(fabsf(sf2 * 10.f)) - logf(11.f);

    #pragma unroll
    for (int s2 = 0; s2 < 4; ++s2) {
        const int pp = tid + s2 * 256;
        const long n = (long)a * NPTS + pp;
        const float sc0 = 0.5f * logf(fabsf(sf0 * sxA[s2])) - logf(fabsf(cvxA[s2]) + 10.f);
        const float sc1 = 0.5f * logf(fabsf(sf1 * syA[s2])) - logf(fabsf(cvyA[s2]) + 10.f);
        out[N4 + n * 3 + 0] = sc0;
        out[N4 + n * 3 + 1] = sc1;
        out[N4 + n * 3 + 2] = sc2;
    }

    // SH synthesis: 48 outputs per point, chunked by 12 so each broadcast
    // LDS read is reused across this thread's 4 points.
    for (int cc = 0; cc < 4; ++cc) {
        float acc[4][12];
        #pragma unroll
        for (int p = 0; p < 4; ++p)
            #pragma unroll
            for (int q = 0; q < 12; ++q) acc[p][q] = 0.f;

        #pragma unroll
        for (int kl = 0; kl < 16; ++kl) {
            const int k = kl >> 2, l = kl & 3;
            const float4 v0 = *reinterpret_cast<const float4*>(&s_sh[kl][cc * 12 + 0]);
            const float4 v1 = *reinterpret_cast<const float4*>(&s_sh[kl][cc * 12 + 4]);
            const float4 v2 = *reinterpret_cast<const float4*>(&s_sh[kl][cc * 12 + 8]);
            #pragma unroll
            for (int p = 0; p < 4; ++p) {
                const float w = buA[p][k] * bvA[p][l];
                acc[p][0]  += w * v0.x; acc[p][1]  += w * v0.y;
                acc[p][2]  += w * v0.z; acc[p][3]  += w * v0.w;
                acc[p][4]  += w * v1.x; acc[p][5]  += w * v1.y;
                acc[p][6]  += w * v1.z; acc[p][7]  += w * v1.w;
                acc[p][8]  += w * v2.x; acc[p][9]  += w * v2.y;
                acc[p][10] += w * v2.z; acc[p][11] += w * v2.w;
            }
        }
        #pragma unroll
        for (int p = 0; p < 4; ++p) {
            const long n = (long)a * NPTS + tid + p * 256;
            float4* dst = reinterpret_cast<float4*>(out + N11 + n * 48 + cc * 12);
            dst[0] = make_float4(acc[p][0], acc[p][1], acc[p][2],  acc[p][3]);
            dst[1] = make_float4(acc[p][4], acc[p][5], acc[p][6],  acc[p][7]);
            dst[2] = make_float4(acc[p][8], acc[p][9], acc[p][10], acc[p][11]);
        }
    }
}

extern "C" void kernel_launch(void* const* d_in, const int* in_sizes, int n_in,
                              void* d_out, int out_size, void* d_ws, size_t ws_size,
                              hipStream_t stream) {
    const float* cp      = (const float*)d_in[0];
    const float* Wt      = (const float*)d_in[1];
    const float* sh_dc   = (const float*)d_in[2];
    const float* sh_rest = (const float*)d_in[3];
    const float* spar    = (const float*)d_in[4];
    const float* opac    = (const float*)d_in[5];
    const float* b_u     = (const float*)d_in[6];
    const float* b_v     = (const float*)d_in[7];
    const float* db_u    = (const float*)d_in[8];
    const float* db_v    = (const float*)d_in[9];
    const float* ddb_u   = (const float*)d_in[10];
    const float* ddb_v   = (const float*)d_in[11];
    float* out = (float*)d_out;

    hipLaunchKernelGGL(spline_fused, dim3(NPATCH), dim3(256), 0, stream,
                       cp, Wt, sh_dc, sh_rest, spar, opac,
                       b_u, b_v, db_u, db_v, ddb_u, ddb_v, out);
}

// Round 2
// 162.654 us; speedup vs baseline: 3.2917x; 3.2917x over previous
//
#include <hip/hip_runtime.h>
#include <math.h>

#define NPATCH 2048
#define RES 32
#define NPTS 1024
#define NTOT (NPATCH * NPTS)

// ---------------------------------------------------------------------------
// Kernel A: geometry — xyz, opacity, scaling, rotation (+ per-patch area mean)
// One block per patch, 256 threads, 4 points/thread.
// ---------------------------------------------------------------------------
__global__ __launch_bounds__(256) void spline_geom(
    const float* __restrict__ cp,       // [P,4,4,3]
    const float* __restrict__ Wt,       // [P,4,4]
    const float* __restrict__ spar,     // [P,2]
    const float* __restrict__ opac,     // [N,1]
    const float* __restrict__ b_u,      // [P,32,4]
    const float* __restrict__ b_v,
    const float* __restrict__ db_u,
    const float* __restrict__ db_v,
    const float* __restrict__ ddb_u,
    const float* __restrict__ ddb_v,
    float* __restrict__ out)
{
    const int a = blockIdx.x;
    const int tid = threadIdx.x;

    __shared__ float s_W[16];
    __shared__ float s_wcp[16][3];
    __shared__ float s_bu[32][4];
    __shared__ float s_bv[32][4];
    __shared__ float s_dbu[32][4];
    __shared__ float s_dbv[32][4];
    __shared__ float s_ddbu[32][4];
    __shared__ float s_ddbv[32][4];
    __shared__ float s_red[4];
    __shared__ float s_area;

    if (tid < 16) s_W[tid] = Wt[a * 16 + tid];
    if (tid < 48) {
        const int kl = tid / 3, m = tid - kl * 3;
        s_wcp[kl][m] = cp[a * 48 + tid] * Wt[a * 16 + kl];
    }
    if (tid < 128) {
        s_bu  [tid >> 2][tid & 3] = b_u  [a * 128 + tid];
        s_bv  [tid >> 2][tid & 3] = b_v  [a * 128 + tid];
        s_dbu [tid >> 2][tid & 3] = db_u [a * 128 + tid];
        s_dbv [tid >> 2][tid & 3] = db_v [a * 128 + tid];
        s_ddbu[tid >> 2][tid & 3] = ddb_u[a * 128 + tid];
        s_ddbv[tid >> 2][tid & 3] = ddb_v[a * 128 + tid];
    }
    __syncthreads();

    const long N3 = 3L * NTOT, N4 = 4L * NTOT, N7 = 7L * NTOT;

    float sxA[4], syA[4], cvxA[4], cvyA[4];
    float area_acc = 0.f;

    #pragma unroll
    for (int s2 = 0; s2 < 4; ++s2) {
        const int pp = tid + s2 * 256;
        const int i = pp >> 5, j = pp & 31;
        float bu[4], bv[4], dbu_[4], dbv_[4], ddbu_[4], ddbv_[4];
        #pragma unroll
        for (int k = 0; k < 4; ++k) {
            bu[k]    = s_bu[i][k];    bv[k]    = s_bv[j][k];
            dbu_[k]  = s_dbu[i][k];   dbv_[k]  = s_dbv[j][k];
            ddbu_[k] = s_ddbu[i][k];  ddbv_[k] = s_ddbv[j][k];
        }

        float den = 0.f;
        float x0 = 0, x1 = 0, x2 = 0;
        float du0 = 0, du1 = 0, du2 = 0, dv0 = 0, dv1 = 0, dv2 = 0;
        float eu0 = 0, eu1 = 0, eu2 = 0, ev0 = 0, ev1 = 0, ev2 = 0;
        #pragma unroll
        for (int kl = 0; kl < 16; ++kl) {
            const int k = kl >> 2, l = kl & 3;
            const float bb  = bu[k] * bv[l];
            const float wdu = dbu_[k] * bv[l];
            const float wdv = bu[k] * dbv_[l];
            const float weu = ddbu_[k] * bv[l];
            const float wev = bu[k] * ddbv_[l];
            den += bb * s_W[kl];
            const float c0 = s_wcp[kl][0], c1 = s_wcp[kl][1], c2 = s_wcp[kl][2];
            x0  += bb  * c0; x1  += bb  * c1; x2  += bb  * c2;
            du0 += wdu * c0; du1 += wdu * c1; du2 += wdu * c2;
            dv0 += wdv * c0; dv1 += wdv * c1; dv2 += wdv * c2;
            eu0 += weu * c0; eu1 += weu * c1; eu2 += weu * c2;
            ev0 += wev * c0; ev1 += wev * c1; ev2 += wev * c2;
        }
        if (den == 0.f) den = 1.f;
        const float inv = 1.0f / den;
        x0 *= inv; x1 *= inv; x2 *= inv;
        du0 *= inv; du1 *= inv; du2 *= inv;
        dv0 *= inv; dv1 *= inv; dv2 *= inv;
        eu0 *= inv; eu1 *= inv; eu2 *= inv;
        ev0 *= inv; ev1 *= inv; ev2 *= inv;

        const float cx = du1 * dv2 - du2 * dv1;
        const float cy = du2 * dv0 - du0 * dv2;
        const float cz = du0 * dv1 - du1 * dv0;
        area_acc += sqrtf(cx * cx + cy * cy + cz * cz);

        float l1 = fabsf(cx) + fabsf(cy) + fabsf(cz);
        l1 = fmaxf(l1, 1e-12f);
        float nx = cx / l1, ny = cy / l1, nz = cz / l1;
        float l2 = sqrtf(nx * nx + ny * ny + nz * nz);
        l2 = fmaxf(l2, 1e-12f);
        nx /= l2; ny /= l2; nz /= l2;
        const float qw = 1.f + nz, qx = -ny, qy = nx;
        float qn = sqrtf(qw * qw + qx * qx + qy * qy);
        qn = fmaxf(qn, 1e-12f);
        const float rqn = 1.0f / qn;

        sxA[s2]  = du0 * du0 + du1 * du1 + du2 * du2 + 10.f;
        syA[s2]  = dv0 * dv0 + dv1 * dv1 + dv2 * dv2 + 10.f;
        cvxA[s2] = eu0 + eu1 + eu2;
        cvyA[s2] = ev0 + ev1 + ev2;

        const long n = (long)a * NPTS + pp;
        out[n * 3 + 0] = x0;
        out[n * 3 + 1] = x1;
        out[n * 3 + 2] = x2;
        out[N3 + n] = opac[n];
        *reinterpret_cast<float4*>(out + N7 + n * 4) =
            make_float4(qw * rqn, qx * rqn, qy * rqn, 0.f);
    }

    // per-patch area mean: wave reduce then cross-wave via LDS
    #pragma unroll
    for (int off = 32; off > 0; off >>= 1)
        area_acc += __shfl_down(area_acc, off, 64);
    if ((tid & 63) == 0) s_red[tid >> 6] = area_acc;
    __syncthreads();
    if (tid == 0) s_area = s_red[0] + s_red[1] + s_red[2] + s_red[3];
    __syncthreads();

    const float factor = s_area * (1.0f / 1024.0f) * (1.0f / 1024.0f); // mean / R^2
    const float sp0 = spar[a * 2 + 0], sp1 = spar[a * 2 + 1];
    const float sf0 = factor * sp0;
    const float sf1 = factor * sp1;
    const float sf2 = factor * 1e-16f;
    const float sc2 = 0.5f * logf(fabsf(sf2 * 10.f)) - logf(11.f);

    #pragma unroll
    for (int s2 = 0; s2 < 4; ++s2) {
        const int pp = tid + s2 * 256;
        const long n = (long)a * NPTS + pp;
        const float sc0 = 0.5f * logf(fabsf(sf0 * sxA[s2])) - logf(fabsf(cvxA[s2]) + 10.f);
        const float sc1 = 0.5f * logf(fabsf(sf1 * syA[s2])) - logf(fabsf(cvyA[s2]) + 10.f);
        out[N4 + n * 3 + 0] = sc0;
        out[N4 + n * 3 + 1] = sc1;
        out[N4 + n * 3 + 2] = sc2;
    }
}

// ---------------------------------------------------------------------------
// Kernel B: SH synthesis — each thread computes ONE output float4 per iter.
// 4 blocks per patch (quarter-patch = 256 points = 3072 float4), 256 threads,
// 12 float4 per thread. Stores are perfectly contiguous (16 B/lane).
// ---------------------------------------------------------------------------
__global__ __launch_bounds__(256) void spline_sh(
    const float* __restrict__ sh_dc,    // [P,4,4,1,3]
    const float* __restrict__ sh_rest,  // [P,4,4,15,3]
    const float* __restrict__ b_u,      // [P,32,4]
    const float* __restrict__ b_v,
    float* __restrict__ out)
{
    const int blk = blockIdx.x;
    const int a = blk >> 2, q = blk & 3;
    const int t = threadIdx.x;

    __shared__ float s_sh[16][48];
    __shared__ float s_bu[8][4];    // rows q*8 .. q*8+7
    __shared__ float s_bv[32][4];

    for (int idx = t; idx < 768; idx += 256) {
        const int kl = idx / 48, c = idx - kl * 48;
        s_sh[kl][c] = (c < 3) ? sh_dc[a * 48 + kl * 3 + c]
                              : sh_rest[a * 720 + kl * 45 + (c - 3)];
    }
    if (t < 32)  s_bu[t >> 2][t & 3] = b_u[a * 128 + q * 32 + t];
    if (t < 128) s_bv[t >> 2][t & 3] = b_v[a * 128 + t];
    __syncthreads();

    float4* __restrict__ out4 =
        reinterpret_cast<float4*>(out + 11L * NTOT) + (long)a * 12288 + q * 3072;

    #pragma unroll
    for (int k = 0; k < 12; ++k) {
        const unsigned f = t + (k << 8);      // 0..3071
        const unsigned p = f / 12u;           // local point 0..255
        const unsigned c = f - p * 12u;       // coeff chunk 0..11
        const int i = p >> 5;                 // local bu row 0..7
        const int j = p & 31;

        const float4 bu = *reinterpret_cast<const float4*>(s_bu[i]);
        const float4 bv = *reinterpret_cast<const float4*>(s_bv[j]);

        float ax = 0.f, ay = 0.f, az = 0.f, aw = 0.f;
        #pragma unroll
        for (int kl = 0; kl < 16; ++kl) {
            const float wu = (kl < 4) ? bu.x : (kl < 8) ? bu.y : (kl < 12) ? bu.z : bu.w;
            const float wv = ((kl & 3) == 0) ? bv.x : ((kl & 3) == 1) ? bv.y
                           : ((kl & 3) == 2) ? bv.z : bv.w;
            const float w = wu * wv;
            const float4 v = *reinterpret_cast<const float4*>(&s_sh[kl][c * 4]);
            ax += w * v.x; ay += w * v.y; az += w * v.z; aw += w * v.w;
        }
        out4[f] = make_float4(ax, ay, az, aw);
    }
}

extern "C" void kernel_launch(void* const* d_in, const int* in_sizes, int n_in,
                              void* d_out, int out_size, void* d_ws, size_t ws_size,
                              hipStream_t stream) {
    const float* cp      = (const float*)d_in[0];
    const float* Wt      = (const float*)d_in[1];
    const float* sh_dc   = (const float*)d_in[2];
    const float* sh_rest = (const float*)d_in[3];
    const float* spar    = (const float*)d_in[4];
    const float* opac    = (const float*)d_in[5];
    const float* b_u     = (const float*)d_in[6];
    const float* b_v     = (const float*)d_in[7];
    const float* db_u    = (const float*)d_in[8];
    const float* db_v    = (const float*)d_in[9];
    const float* ddb_u   = (const float*)d_in[10];
    const float* ddb_v   = (const float*)d_in[11];
    float* out = (float*)d_out;

    hipLaunchKernelGGL(spline_geom, dim3(NPATCH), dim3(256), 0, stream,
                       cp, Wt, spar, opac,
                       b_u, b_v, db_u, db_v, ddb_u, ddb_v, out);
    hipLaunchKernelGGL(spline_sh, dim3(NPATCH * 4), dim3(256), 0, stream,
                       sh_dc, sh_rest, b_u, b_v, out);
}

// Round 3
// 142.535 us; speedup vs baseline: 3.7563x; 1.1411x over previous
//
#include <hip/hip_runtime.h>
#include <math.h>

#define NPATCH 2048
#define RES 32
#define NPTS 1024
#define NTOT (NPATCH * NPTS)

// ---------------------------------------------------------------------------
// Kernel A: geometry — xyz, opacity, scaling, rotation (+ per-patch area mean)
// One block per patch, 1024 threads, ONE point per thread (short critical path).
// ---------------------------------------------------------------------------
__global__ __launch_bounds__(1024) void spline_geom(
    const float* __restrict__ cp,       // [P,4,4,3]
    const float* __restrict__ Wt,       // [P,4,4]
    const float* __restrict__ spar,     // [P,2]
    const float* __restrict__ opac,     // [N,1]
    const float* __restrict__ b_u,      // [P,32,4]
    const float* __restrict__ b_v,
    const float* __restrict__ db_u,
    const float* __restrict__ db_v,
    const float* __restrict__ ddb_u,
    const float* __restrict__ ddb_v,
    float* __restrict__ out)
{
    const int a = blockIdx.x;
    const int tid = threadIdx.x;

    __shared__ float s_W[16];
    __shared__ float s_wcp[16][3];
    __shared__ float s_bu[32][4];
    __shared__ float s_bv[32][4];
    __shared__ float s_dbu[32][4];
    __shared__ float s_dbv[32][4];
    __shared__ float s_ddbu[32][4];
    __shared__ float s_ddbv[32][4];
    __shared__ float s_red[16];
    __shared__ float s_area;

    if (tid < 16) s_W[tid] = Wt[a * 16 + tid];
    if (tid < 48) {
        const int kl = tid / 3, m = tid - kl * 3;
        s_wcp[kl][m] = cp[a * 48 + tid] * Wt[a * 16 + kl];
    }
    if (tid < 128) {
        s_bu  [tid >> 2][tid & 3] = b_u  [a * 128 + tid];
        s_bv  [tid >> 2][tid & 3] = b_v  [a * 128 + tid];
        s_dbu [tid >> 2][tid & 3] = db_u [a * 128 + tid];
        s_dbv [tid >> 2][tid & 3] = db_v [a * 128 + tid];
        s_ddbu[tid >> 2][tid & 3] = ddb_u[a * 128 + tid];
        s_ddbv[tid >> 2][tid & 3] = ddb_v[a * 128 + tid];
    }
    __syncthreads();

    const long N3 = 3L * NTOT, N4 = 4L * NTOT, N7 = 7L * NTOT;

    const int i = tid >> 5, j = tid & 31;
    float bu[4], bv[4], dbu_[4], dbv_[4], ddbu_[4], ddbv_[4];
    #pragma unroll
    for (int k = 0; k < 4; ++k) {
        bu[k]    = s_bu[i][k];    bv[k]    = s_bv[j][k];
        dbu_[k]  = s_dbu[i][k];   dbv_[k]  = s_dbv[j][k];
        ddbu_[k] = s_ddbu[i][k];  ddbv_[k] = s_ddbv[j][k];
    }

    float den = 0.f;
    float x0 = 0, x1 = 0, x2 = 0;
    float du0 = 0, du1 = 0, du2 = 0, dv0 = 0, dv1 = 0, dv2 = 0;
    float eu0 = 0, eu1 = 0, eu2 = 0, ev0 = 0, ev1 = 0, ev2 = 0;
    #pragma unroll
    for (int kl = 0; kl < 16; ++kl) {
        const int k = kl >> 2, l = kl & 3;
        const float bb  = bu[k] * bv[l];
        const float wdu = dbu_[k] * bv[l];
        const float wdv = bu[k] * dbv_[l];
        const float weu = ddbu_[k] * bv[l];
        const float wev = bu[k] * ddbv_[l];
        den += bb * s_W[kl];
        const float c0 = s_wcp[kl][0], c1 = s_wcp[kl][1], c2 = s_wcp[kl][2];
        x0  += bb  * c0; x1  += bb  * c1; x2  += bb  * c2;
        du0 += wdu * c0; du1 += wdu * c1; du2 += wdu * c2;
        dv0 += wdv * c0; dv1 += wdv * c1; dv2 += wdv * c2;
        eu0 += weu * c0; eu1 += weu * c1; eu2 += weu * c2;
        ev0 += wev * c0; ev1 += wev * c1; ev2 += wev * c2;
    }
    if (den == 0.f) den = 1.f;
    const float inv = 1.0f / den;
    x0 *= inv; x1 *= inv; x2 *= inv;
    du0 *= inv; du1 *= inv; du2 *= inv;
    dv0 *= inv; dv1 *= inv; dv2 *= inv;
    eu0 *= inv; eu1 *= inv; eu2 *= inv;
    ev0 *= inv; ev1 *= inv; ev2 *= inv;

    const float cx = du1 * dv2 - du2 * dv1;
    const float cy = du2 * dv0 - du0 * dv2;
    const float cz = du0 * dv1 - du1 * dv0;
    float area_acc = sqrtf(cx * cx + cy * cy + cz * cz);

    float l1 = fabsf(cx) + fabsf(cy) + fabsf(cz);
    l1 = fmaxf(l1, 1e-12f);
    float nx = cx / l1, ny = cy / l1, nz = cz / l1;
    float l2 = sqrtf(nx * nx + ny * ny + nz * nz);
    l2 = fmaxf(l2, 1e-12f);
    nx /= l2; ny /= l2; nz /= l2;
    const float qw = 1.f + nz, qx = -ny, qy = nx;
    float qn = sqrtf(qw * qw + qx * qx + qy * qy);
    qn = fmaxf(qn, 1e-12f);
    const float rqn = 1.0f / qn;

    const float sx  = du0 * du0 + du1 * du1 + du2 * du2 + 10.f;
    const float sy  = dv0 * dv0 + dv1 * dv1 + dv2 * dv2 + 10.f;
    const float cvx = eu0 + eu1 + eu2;
    const float cvy = ev0 + ev1 + ev2;

    const long n = (long)a * NPTS + tid;
    out[n * 3 + 0] = x0;
    out[n * 3 + 1] = x1;
    out[n * 3 + 2] = x2;
    out[N3 + n] = opac[n];
    *reinterpret_cast<float4*>(out + N7 + n * 4) =
        make_float4(qw * rqn, qx * rqn, qy * rqn, 0.f);

    // per-patch area mean: wave reduce then cross-wave via LDS
    #pragma unroll
    for (int off = 32; off > 0; off >>= 1)
        area_acc += __shfl_down(area_acc, off, 64);
    if ((tid & 63) == 0) s_red[tid >> 6] = area_acc;
    __syncthreads();
    if (tid == 0) {
        float s = 0.f;
        #pragma unroll
        for (int w = 0; w < 16; ++w) s += s_red[w];
        s_area = s;
    }
    __syncthreads();

    const float factor = s_area * (1.0f / 1024.0f) * (1.0f / 1024.0f); // mean / R^2
    const float sp0 = spar[a * 2 + 0], sp1 = spar[a * 2 + 1];
    const float sf0 = factor * sp0;
    const float sf1 = factor * sp1;
    const float sf2 = factor * 1e-16f;
    const float sc2 = 0.5f * logf(fabsf(sf2 * 10.f)) - logf(11.f);

    const float sc0 = 0.5f * logf(fabsf(sf0 * sx)) - logf(fabsf(cvx) + 10.f);
    const float sc1 = 0.5f * logf(fabsf(sf1 * sy)) - logf(fabsf(cvy) + 10.f);
    out[N4 + n * 3 + 0] = sc0;
    out[N4 + n * 3 + 1] = sc1;
    out[N4 + n * 3 + 2] = sc2;
}

// ---------------------------------------------------------------------------
// Kernel B: SH synthesis, separable two-stage contraction.
//   stage1: tmp[i][l][m] = sum_k bu[i][k] * sh[k][l][m]   (per block, 8 i-rows)
//   stage2: out[p][c]    = sum_l bv[j][l] * tmp[i][l][c]  (4 reads per float4)
// 4 blocks/patch, 256 threads; stores perfectly contiguous (16 B/lane).
// ---------------------------------------------------------------------------
__global__ __launch_bounds__(256) void spline_sh(
    const float* __restrict__ sh_dc,    // [P,4,4,1,3]
    const float* __restrict__ sh_rest,  // [P,4,4,15,3]
    const float* __restrict__ b_u,      // [P,32,4]
    const float* __restrict__ b_v,
    float* __restrict__ out)
{
    const int blk = blockIdx.x;
    const int a = blk >> 2, q = blk & 3;
    const int t = threadIdx.x;

    __shared__ float s_sh[16][48];
    __shared__ float s_bu[8][4];        // this block's 8 u-rows
    __shared__ float s_bv[32][4];
    __shared__ float s_tmp[8 * 4 * 52]; // [i][l][m] padded: row stride 52 floats

    for (int idx = t; idx < 768; idx += 256) {
        const int kl = idx / 48, c = idx - kl * 48;
        s_sh[kl][c] = (c < 3) ? sh_dc[a * 48 + kl * 3 + c]
                              : sh_rest[a * 720 + kl * 45 + (c - 3)];
    }
    if (t < 32)  s_bu[t >> 2][t & 3] = b_u[a * 128 + q * 32 + t];
    if (t < 128) s_bv[t >> 2][t & 3] = b_v[a * 128 + t];
    __syncthreads();

    // stage 1: 384 float4 elements, <=2 per thread
    #pragma unroll
    for (int r = 0; r < 2; ++r) {
        const int e4 = t + r * 256;
        if (e4 < 384) {
            const int i = e4 / 48, rem = e4 - i * 48;
            const int l = rem / 12, cq = rem - l * 12;
            float ax = 0.f, ay = 0.f, az = 0.f, aw = 0.f;
            #pragma unroll
            for (int k = 0; k < 4; ++k) {
                const float w = s_bu[i][k];
                const float4 v = *reinterpret_cast<const float4*>(&s_sh[k * 4 + l][cq * 4]);
                ax += w * v.x; ay += w * v.y; az += w * v.z; aw += w * v.w;
            }
            *reinterpret_cast<float4*>(&s_tmp[i * 208 + l * 52 + cq * 4]) =
                make_float4(ax, ay, az, aw);
        }
    }
    __syncthreads();

    float4* __restrict__ out4 =
        reinterpret_cast<float4*>(out + 11L * NTOT) + (long)a * 12288 + q * 3072;

    #pragma unroll
    for (int k = 0; k < 12; ++k) {
        const unsigned f = t + (k << 8);      // 0..3071
        const unsigned p = f / 12u;           // local point 0..255
        const unsigned c = f - p * 12u;       // coeff chunk 0..11
        const int i = p >> 5;                 // local bu row 0..7
        const int j = p & 31;

        const float4 bv = *reinterpret_cast<const float4*>(s_bv[j]);
        const float* base = &s_tmp[i * 208 + c * 4];

        const float4 t0 = *reinterpret_cast<const float4*>(base + 0 * 52);
        const float4 t1 = *reinterpret_cast<const float4*>(base + 1 * 52);
        const float4 t2 = *reinterpret_cast<const float4*>(base + 2 * 52);
        const float4 t3 = *reinterpret_cast<const float4*>(base + 3 * 52);

        float ax = bv.x * t0.x + bv.y * t1.x + bv.z * t2.x + bv.w * t3.x;
        float ay = bv.x * t0.y + bv.y * t1.y + bv.z * t2.y + bv.w * t3.y;
        float az = bv.x * t0.z + bv.y * t1.z + bv.z * t2.z + bv.w * t3.z;
        float aw = bv.x * t0.w + bv.y * t1.w + bv.z * t2.w + bv.w * t3.w;

        out4[f] = make_float4(ax, ay, az, aw);
    }
}

extern "C" void kernel_launch(void* const* d_in, const int* in_sizes, int n_in,
                              void* d_out, int out_size, void* d_ws, size_t ws_size,
                              hipStream_t stream) {
    const float* cp      = (const float*)d_in[0];
    const float* Wt      = (const float*)d_in[1];
    const float* sh_dc   = (const float*)d_in[2];
    const float* sh_rest = (const float*)d_in[3];
    const float* spar    = (const float*)d_in[4];
    const float* opac    = (const float*)d_in[5];
    const float* b_u     = (const float*)d_in[6];
    const float* b_v     = (const float*)d_in[7];
    const float* db_u    = (const float*)d_in[8];
    const float* db_v    = (const float*)d_in[9];
    const float* ddb_u   = (const float*)d_in[10];
    const float* ddb_v   = (const float*)d_in[11];
    float* out = (float*)d_out;

    hipLaunchKernelGGL(spline_geom, dim3(NPATCH), dim3(1024), 0, stream,
                       cp, Wt, spar, opac,
                       b_u, b_v, db_u, db_v, ddb_u, ddb_v, out);
    hipLaunchKernelGGL(spline_sh, dim3(NPATCH * 4), dim3(256), 0, stream,
                       sh_dc, sh_rest, b_u, b_v, out);
}

// Round 4
// 141.565 us; speedup vs baseline: 3.7821x; 1.0069x over previous
//
#include <hip/hip_runtime.h>
#include <math.h>

#define NPATCH 2048
#define RES 32
#define NPTS 1024
#define NTOT (NPATCH * NPTS)

// ---------------------------------------------------------------------------
// Prologue: per-patch area sum -> ws[a].  Recomputes du/dv only (cheap VALU),
// deterministic block reduction, no atomics.  2048 blocks x 256 thr, 4 pt/thr.
// ---------------------------------------------------------------------------
__global__ __launch_bounds__(256) void area_kernel(
    const float* __restrict__ cp,       // [P,4,4,3]
    const float* __restrict__ Wt,       // [P,4,4]
    const float* __restrict__ b_u,      // [P,32,4]
    const float* __restrict__ b_v,
    const float* __restrict__ db_u,
    const float* __restrict__ db_v,
    float* __restrict__ ws)
{
    const int a = blockIdx.x;
    const int tid = threadIdx.x;

    __shared__ float s_W[16];
    __shared__ float s_wcp[16][3];
    __shared__ float s_bu[32][4];
    __shared__ float s_bv[32][4];
    __shared__ float s_dbu[32][4];
    __shared__ float s_dbv[32][4];
    __shared__ float s_red[4];

    if (tid < 16) s_W[tid] = Wt[a * 16 + tid];
    if (tid < 48) {
        const int kl = tid / 3, m = tid - kl * 3;
        s_wcp[kl][m] = cp[a * 48 + tid] * Wt[a * 16 + kl];
    }
    if (tid < 128) {
        s_bu [tid >> 2][tid & 3] = b_u [a * 128 + tid];
        s_bv [tid >> 2][tid & 3] = b_v [a * 128 + tid];
        s_dbu[tid >> 2][tid & 3] = db_u[a * 128 + tid];
        s_dbv[tid >> 2][tid & 3] = db_v[a * 128 + tid];
    }
    __syncthreads();

    float acc = 0.f;
    #pragma unroll
    for (int s2 = 0; s2 < 4; ++s2) {
        const int pp = tid + s2 * 256;
        const int i = pp >> 5, j = pp & 31;
        float den = 0.f;
        float du0 = 0, du1 = 0, du2 = 0, dv0 = 0, dv1 = 0, dv2 = 0;
        #pragma unroll
        for (int kl = 0; kl < 16; ++kl) {
            const int k = kl >> 2, l = kl & 3;
            const float bb  = s_bu[i][k] * s_bv[j][l];
            const float wdu = s_dbu[i][k] * s_bv[j][l];
            const float wdv = s_bu[i][k] * s_dbv[j][l];
            den += bb * s_W[kl];
            const float c0 = s_wcp[kl][0], c1 = s_wcp[kl][1], c2 = s_wcp[kl][2];
            du0 += wdu * c0; du1 += wdu * c1; du2 += wdu * c2;
            dv0 += wdv * c0; dv1 += wdv * c1; dv2 += wdv * c2;
        }
        if (den == 0.f) den = 1.f;
        const float inv = 1.0f / den;
        // |(du/den) x (dv/den)| = |du x dv| * inv^2
        const float cx = du1 * dv2 - du2 * dv1;
        const float cy = du2 * dv0 - du0 * dv2;
        const float cz = du0 * dv1 - du1 * dv0;
        acc += sqrtf(cx * cx + cy * cy + cz * cz) * inv * inv;
    }

    #pragma unroll
    for (int off = 32; off > 0; off >>= 1)
        acc += __shfl_down(acc, off, 64);
    if ((tid & 63) == 0) s_red[tid >> 6] = acc;
    __syncthreads();
    if (tid == 0) ws[a] = s_red[0] + s_red[1] + s_red[2] + s_red[3];
}

// ---------------------------------------------------------------------------
// Fused kernel: 16384 blocks x 256 threads.
//   blk <  8192 : SH quarter-patch (separable two-stage contraction)
//   blk >= 8192 : geometry quarter-patch (1 point/thread), factor from ws
// Both write streams flow concurrently -> HBM-write roofline.
// ---------------------------------------------------------------------------
__global__ __launch_bounds__(256) void fused_kernel(
    const float* __restrict__ cp,       // [P,4,4,3]
    const float* __restrict__ Wt,       // [P,4,4]
    const float* __restrict__ sh_dc,    // [P,4,4,1,3]
    const float* __restrict__ sh_rest,  // [P,4,4,15,3]
    const float* __restrict__ spar,     // [P,2]
    const float* __restrict__ opac,     // [N,1]
    const float* __restrict__ b_u,      // [P,32,4]
    const float* __restrict__ b_v,
    const float* __restrict__ db_u,
    const float* __restrict__ db_v,
    const float* __restrict__ ddb_u,
    const float* __restrict__ ddb_v,
    const float* __restrict__ ws,
    float* __restrict__ out)
{
    const int blk = blockIdx.x;
    const int t = threadIdx.x;

    if (blk < 8192) {
        // ------------------------- SH path -------------------------
        const int a = blk >> 2, q = blk & 3;

        __shared__ float s_sh[16][48];
        __shared__ float s_bu[8][4];
        __shared__ float s_bv[32][4];
        __shared__ float s_tmp[8 * 4 * 52];   // [i][l][m], row stride 52

        for (int idx = t; idx < 768; idx += 256) {
            const int kl = idx / 48, c = idx - kl * 48;
            s_sh[kl][c] = (c < 3) ? sh_dc[a * 48 + kl * 3 + c]
                                  : sh_rest[a * 720 + kl * 45 + (c - 3)];
        }
        if (t < 32)  s_bu[t >> 2][t & 3] = b_u[a * 128 + q * 32 + t];
        if (t < 128) s_bv[t >> 2][t & 3] = b_v[a * 128 + t];
        __syncthreads();

        // stage 1: tmp[i][l][m] = sum_k bu[i][k] * sh[k*4+l][m]
        #pragma unroll
        for (int r = 0; r < 2; ++r) {
            const int e4 = t + r * 256;
            if (e4 < 384) {
                const int i = e4 / 48, rem = e4 - i * 48;
                const int l = rem / 12, cq = rem - l * 12;
                float ax = 0.f, ay = 0.f, az = 0.f, aw = 0.f;
                #pragma unroll
                for (int k = 0; k < 4; ++k) {
                    const float w = s_bu[i][k];
                    const float4 v = *reinterpret_cast<const float4*>(&s_sh[k * 4 + l][cq * 4]);
                    ax += w * v.x; ay += w * v.y; az += w * v.z; aw += w * v.w;
                }
                *reinterpret_cast<float4*>(&s_tmp[i * 208 + l * 52 + cq * 4]) =
                    make_float4(ax, ay, az, aw);
            }
        }
        __syncthreads();

        float4* __restrict__ out4 =
            reinterpret_cast<float4*>(out + 11L * NTOT) + (long)a * 12288 + q * 3072;

        #pragma unroll
        for (int k = 0; k < 12; ++k) {
            const unsigned f = t + (k << 8);
            const unsigned p = f / 12u;
            const unsigned c = f - p * 12u;
            const int i = p >> 5;
            const int j = p & 31;

            const float4 bv = *reinterpret_cast<const float4*>(s_bv[j]);
            const float* base = &s_tmp[i * 208 + c * 4];

            const float4 t0 = *reinterpret_cast<const float4*>(base + 0 * 52);
            const float4 t1 = *reinterpret_cast<const float4*>(base + 1 * 52);
            const float4 t2 = *reinterpret_cast<const float4*>(base + 2 * 52);
            const float4 t3 = *reinterpret_cast<const float4*>(base + 3 * 52);

            out4[f] = make_float4(
                bv.x * t0.x + bv.y * t1.x + bv.z * t2.x + bv.w * t3.x,
                bv.x * t0.y + bv.y * t1.y + bv.z * t2.y + bv.w * t3.y,
                bv.x * t0.z + bv.y * t1.z + bv.z * t2.z + bv.w * t3.z,
                bv.x * t0.w + bv.y * t1.w + bv.z * t2.w + bv.w * t3.w);
        }
    } else {
        // ----------------------- geometry path -----------------------
        const int g = blk - 8192;
        const int a = g >> 2, q = g & 3;

        __shared__ float g_W[16];
        __shared__ float g_wcp[16][3];
        __shared__ float g_bu[8][4];
        __shared__ float g_bv[32][4];
        __shared__ float g_dbu[8][4];
        __shared__ float g_dbv[32][4];
        __shared__ float g_ddbu[8][4];
        __shared__ float g_ddbv[32][4];

        if (t < 16) g_W[t] = Wt[a * 16 + t];
        if (t < 48) {
            const int kl = t / 3, m = t - kl * 3;
            g_wcp[kl][m] = cp[a * 48 + t] * Wt[a * 16 + kl];
        }
        if (t < 32) {
            g_bu  [t >> 2][t & 3] = b_u  [a * 128 + q * 32 + t];
            g_dbu [t >> 2][t & 3] = db_u [a * 128 + q * 32 + t];
            g_ddbu[t >> 2][t & 3] = ddb_u[a * 128 + q * 32 + t];
        }
        if (t < 128) {
            g_bv  [t >> 2][t & 3] = b_v  [a * 128 + t];
            g_dbv [t >> 2][t & 3] = db_v [a * 128 + t];
            g_ddbv[t >> 2][t & 3] = ddb_v[a * 128 + t];
        }
        __syncthreads();

        const long N3 = 3L * NTOT, N4 = 4L * NTOT, N7 = 7L * NTOT;

        const int i = t >> 5, j = t & 31;     // local u-row, v-col
        float bu[4], bv[4], dbu_[4], dbv_[4], ddbu_[4], ddbv_[4];
        #pragma unroll
        for (int k = 0; k < 4; ++k) {
            bu[k]    = g_bu[i][k];    bv[k]    = g_bv[j][k];
            dbu_[k]  = g_dbu[i][k];   dbv_[k]  = g_dbv[j][k];
            ddbu_[k] = g_ddbu[i][k];  ddbv_[k] = g_ddbv[j][k];
        }

        float den = 0.f;
        float x0 = 0, x1 = 0, x2 = 0;
        float du0 = 0, du1 = 0, du2 = 0, dv0 = 0, dv1 = 0, dv2 = 0;
        float eu0 = 0, eu1 = 0, eu2 = 0, ev0 = 0, ev1 = 0, ev2 = 0;
        #pragma unroll
        for (int kl = 0; kl < 16; ++kl) {
            const int k = kl >> 2, l = kl & 3;
            const float bb  = bu[k] * bv[l];
            const float wdu = dbu_[k] * bv[l];
            const float wdv = bu[k] * dbv_[l];
            const float weu = ddbu_[k] * bv[l];
            const float wev = bu[k] * ddbv_[l];
            den += bb * g_W[kl];
            const float c0 = g_wcp[kl][0], c1 = g_wcp[kl][1], c2 = g_wcp[kl][2];
            x0  += bb  * c0; x1  += bb  * c1; x2  += bb  * c2;
            du0 += wdu * c0; du1 += wdu * c1; du2 += wdu * c2;
            dv0 += wdv * c0; dv1 += wdv * c1; dv2 += wdv * c2;
            eu0 += weu * c0; eu1 += weu * c1; eu2 += weu * c2;
            ev0 += wev * c0; ev1 += wev * c1; ev2 += wev * c2;
        }
        if (den == 0.f) den = 1.f;
        const float inv = 1.0f / den;
        x0 *= inv; x1 *= inv; x2 *= inv;
        du0 *= inv; du1 *= inv; du2 *= inv;
        dv0 *= inv; dv1 *= inv; dv2 *= inv;
        eu0 *= inv; eu1 *= inv; eu2 *= inv;
        ev0 *= inv; ev1 *= inv; ev2 *= inv;

        const float cx = du1 * dv2 - du2 * dv1;
        const float cy = du2 * dv0 - du0 * dv2;
        const float cz = du0 * dv1 - du1 * dv0;

        float l1 = fabsf(cx) + fabsf(cy) + fabsf(cz);
        l1 = fmaxf(l1, 1e-12f);
        float nx = cx / l1, ny = cy / l1, nz = cz / l1;
        float l2 = sqrtf(nx * nx + ny * ny + nz * nz);
        l2 = fmaxf(l2, 1e-12f);
        nx /= l2; ny /= l2; nz /= l2;
        const float qw = 1.f + nz, qx = -ny, qy = nx;
        float qn = sqrtf(qw * qw + qx * qx + qy * qy);
        qn = fmaxf(qn, 1e-12f);
        const float rqn = 1.0f / qn;

        const float sx  = du0 * du0 + du1 * du1 + du2 * du2 + 10.f;
        const float sy  = dv0 * dv0 + dv1 * dv1 + dv2 * dv2 + 10.f;
        const float cvx = eu0 + eu1 + eu2;
        const float cvy = ev0 + ev1 + ev2;

        const float factor = ws[a] * (1.0f / 1024.0f) * (1.0f / 1024.0f);
        const float sp0 = spar[a * 2 + 0], sp1 = spar[a * 2 + 1];
        const float sf0 = factor * sp0;
        const float sf1 = factor * sp1;
        const float sf2 = factor * 1e-16f;

        const long n = (long)a * NPTS + q * 256 + t;
        out[n * 3 + 0] = x0;
        out[n * 3 + 1] = x1;
        out[n * 3 + 2] = x2;
        out[N3 + n] = opac[n];
        *reinterpret_cast<float4*>(out + N7 + n * 4) =
            make_float4(qw * rqn, qx * rqn, qy * rqn, 0.f);

        const float sc0 = 0.5f * __logf(fabsf(sf0 * sx)) - __logf(fabsf(cvx) + 10.f);
        const float sc1 = 0.5f * __logf(fabsf(sf1 * sy)) - __logf(fabsf(cvy) + 10.f);
        const float sc2 = 0.5f * __logf(fabsf(sf2 * 10.f)) - __logf(11.f);
        out[N4 + n * 3 + 0] = sc0;
        out[N4 + n * 3 + 1] = sc1;
        out[N4 + n * 3 + 2] = sc2;
    }
}

extern "C" void kernel_launch(void* const* d_in, const int* in_sizes, int n_in,
                              void* d_out, int out_size, void* d_ws, size_t ws_size,
                              hipStream_t stream) {
    const float* cp      = (const float*)d_in[0];
    const float* Wt      = (const float*)d_in[1];
    const float* sh_dc   = (const float*)d_in[2];
    const float* sh_rest = (const float*)d_in[3];
    const float* spar    = (const float*)d_in[4];
    const float* opac    = (const float*)d_in[5];
    const float* b_u     = (const float*)d_in[6];
    const float* b_v     = (const float*)d_in[7];
    const float* db_u    = (const float*)d_in[8];
    const float* db_v    = (const float*)d_in[9];
    const float* ddb_u   = (const float*)d_in[10];
    const float* ddb_v   = (const float*)d_in[11];
    float* out = (float*)d_out;
    float* ws  = (float*)d_ws;

    hipLaunchKernelGGL(area_kernel, dim3(NPATCH), dim3(256), 0, stream,
                       cp, Wt, b_u, b_v, db_u, db_v, ws);
    hipLaunchKernelGGL(fused_kernel, dim3(16384), dim3(256), 0, stream,
                       cp, Wt, sh_dc, sh_rest, spar, opac,
                       b_u, b_v, db_u, db_v, ddb_u, ddb_v, ws, out);
}